// Round 2
// baseline (1116.257 us; speedup 1.0000x reference)
//
#include <hip/hip_runtime.h>

typedef __attribute__((ext_vector_type(8))) short  short8;
typedef __attribute__((ext_vector_type(8))) __bf16 bf16x8;
typedef __attribute__((ext_vector_type(4))) float  f32x4;

union Frag { short8 s; bf16x8 b; };

__device__ __forceinline__ short f2b(float f) {
    unsigned int u = __float_as_uint(f);
    u += 0x7FFF + ((u >> 16) & 1);          // round-to-nearest-even
    return (short)(u >> 16);
}

#define MFMA16(a, b, c) __builtin_amdgcn_mfma_f32_16x16x32_bf16((a), (b), (c), 0, 0, 0)

// C/D layout (16x16x32): col = lane&15, row = (lane>>4)*4 + reg   [m89]
// A/B layout: row/n = lane&15, k = (lane>>4)*8 + j                [m120]
__device__ __forceinline__ void store_cd(short* base, int q, int c,
                                         const f32x4 acc, float bias,
                                         bool relu, int colBase) {
#pragma unroll
    for (int rI = 0; rI < 4; rI++) {
        float v = acc[rI] + bias;
        if (relu) v = fmaxf(v, 0.f);
        base[(q * 4 + rI) * 72 + colBase + c] = f2b(v);
    }
}

__global__ __launch_bounds__(256) void kilonerf_kernel(
    const float* __restrict__ X,
    const float* __restrict__ W0g, const float* __restrict__ b0g,
    const float* __restrict__ W1g, const float* __restrict__ b1g,
    const float* __restrict__ Wag, const float* __restrict__ bag,
    const float* __restrict__ Wfg, const float* __restrict__ bfg,
    const float* __restrict__ Wdg, const float* __restrict__ bdg,
    const float* __restrict__ Wrg, const float* __restrict__ brg,
    float* __restrict__ Out)
{
    __shared__ __align__(16) short W0L[32 * 64];   // K padded 63->64 (zero)
    __shared__ __align__(16) short W1L[32 * 32];
    __shared__ __align__(16) short WfL[32 * 32];
    __shared__ __align__(16) short WdL[32 * 64];   // K padded 59->64 (zero)
    __shared__ __align__(16) short WFinL[16 * 64]; // rows0-2: Wr @k32..63, row3: Wa @k0..31
    __shared__ float bLall[132];                   // b0,b1,bf,bd,[br0,br1,br2,ba]
    __shared__ __align__(16) short hBuf[4][16 * 72];   // cols0..31: h0 then hd; cols32..63: h1
    __shared__ __align__(16) short hdBuf[4][16 * 72];  // cols0..31: feature; 32..58: dir; 59..63: 0
    __shared__ __align__(16) float outF[4][16 * 4];

    const int tid = threadIdx.x;
    const int net = blockIdx.x;

    // ---- stage weights once per network: fp32 -> bf16 into LDS ----
    for (int i = tid; i < 2048; i += 256) {
        int n = i >> 6, k = i & 63;
        W0L[i] = (k < 63) ? f2b(W0g[(net * 32 + n) * 63 + k]) : (short)0;
    }
    for (int i = tid; i < 1024; i += 256) W1L[i] = f2b(W1g[net * 1024 + i]);
    for (int i = tid; i < 1024; i += 256) WfL[i] = f2b(Wfg[net * 1024 + i]);
    for (int i = tid; i < 2048; i += 256) {
        int n = i >> 6, k = i & 63;
        WdL[i] = (k < 59) ? f2b(Wdg[(net * 32 + n) * 59 + k]) : (short)0;
    }
    for (int i = tid; i < 1024; i += 256) {
        int o = i >> 6, k = i & 63;
        short v = 0;
        if (o < 3 && k >= 32) v = f2b(Wrg[(net * 3 + o) * 32 + (k - 32)]);
        else if (o == 3 && k < 32) v = f2b(Wag[net * 32 + k]);
        WFinL[i] = v;
    }
    for (int i = tid; i < 132; i += 256) {
        float v;
        if (i < 32)       v = b0g[net * 32 + i];
        else if (i < 64)  v = b1g[net * 32 + i - 32];
        else if (i < 96)  v = bfg[net * 32 + i - 64];
        else if (i < 128) v = bdg[net * 32 + i - 96];
        else if (i < 131) v = brg[net * 3 + i - 128];
        else              v = bag[net];
        bLall[i] = v;
    }

    const int lane = tid & 63;
    const int w    = tid >> 6;
    const int r    = lane & 15;   // A/B operand row (M or N index)
    const int q    = lane >> 4;   // quad -> k-block
    const int kb   = q * 8;

    short* hW  = hBuf[w];
    short* hdW = hdBuf[w];
    float* oF  = outF[w];

    // zero hd-input pad cols 59..63 once
    for (int i = lane; i < 80; i += 64) {
        int rr = i / 5, cc = i % 5;
        hdW[rr * 72 + 59 + cc] = 0;
    }
    __syncthreads();

    // ---- B-fragments into registers (fixed per network) ----
    Frag B0[2][2], B1[2], Bf[2], Bd[2][2], BF[2];
#pragma unroll
    for (int nt = 0; nt < 2; nt++) {
#pragma unroll
        for (int ks = 0; ks < 2; ks++) {
            B0[nt][ks].s = *(const short8*)&W0L[(nt * 16 + r) * 64 + ks * 32 + kb];
            Bd[nt][ks].s = *(const short8*)&WdL[(nt * 16 + r) * 64 + ks * 32 + kb];
        }
        B1[nt].s = *(const short8*)&W1L[(nt * 16 + r) * 32 + kb];
        Bf[nt].s = *(const short8*)&WfL[(nt * 16 + r) * 32 + kb];
    }
    BF[0].s = *(const short8*)&WFinL[r * 64 + kb];
    BF[1].s = *(const short8*)&WFinL[r * 64 + 32 + kb];

    const int c = r;  // C/D column for this lane
    float b0v[2] = { bLall[c],       bLall[16 + c] };
    float b1v[2] = { bLall[32 + c],  bLall[48 + c] };
    float bfv[2] = { bLall[64 + c],  bLall[80 + c] };
    float bdv[2] = { bLall[96 + c],  bLall[112 + c] };
    float bFinv  = (c < 4) ? bLall[128 + c] : 0.f;

    for (int mt = 0; mt < 8; mt++) {
        const int row0 = net * 512 + w * 128 + mt * 16;

        // ---- dir staging: 16 rows x 27 floats -> bf16 -> hdW cols 32..58 ----
#pragma unroll
        for (int i = 0; i < 7; i++) {
            int idx = i * 64 + lane;
            if (idx < 432) {
                int rr = idx / 27, cc = idx - rr * 27;
                hdW[rr * 72 + 32 + cc] = f2b(X[(size_t)(row0 + rr) * 90 + 63 + cc]);
            }
        }

        // ---- L0: A frags from global fp32 x, converted (k=63 pad killed by zero W0 col) ----
        Frag a0[2];
        {
            const float* px = X + (size_t)(row0 + r) * 90;
#pragma unroll
            for (int ks = 0; ks < 2; ks++)
#pragma unroll
                for (int j = 0; j < 8; j++)
                    a0[ks].s[j] = f2b(px[ks * 32 + q * 8 + j]);
        }
        f32x4 acc0[2] = { {0.f,0.f,0.f,0.f}, {0.f,0.f,0.f,0.f} };
        acc0[0] = MFMA16(a0[0].b, B0[0][0].b, acc0[0]);
        acc0[0] = MFMA16(a0[1].b, B0[0][1].b, acc0[0]);
        acc0[1] = MFMA16(a0[0].b, B0[1][0].b, acc0[1]);
        acc0[1] = MFMA16(a0[1].b, B0[1][1].b, acc0[1]);
        store_cd(hW, q, c, acc0[0], b0v[0], true, 0);    // h0 -> cols 0..31
        store_cd(hW, q, c, acc0[1], b0v[1], true, 16);
        __syncthreads();

        // ---- L1: h0 (cols 0..31) -> h1 (cols 32..63) ----
        Frag a1; a1.s = *(const short8*)&hW[r * 72 + kb];
        f32x4 acc1[2] = { {0.f,0.f,0.f,0.f}, {0.f,0.f,0.f,0.f} };
        acc1[0] = MFMA16(a1.b, B1[0].b, acc1[0]);
        acc1[1] = MFMA16(a1.b, B1[1].b, acc1[1]);
        store_cd(hW, q, c, acc1[0], b1v[0], true, 32);
        store_cd(hW, q, c, acc1[1], b1v[1], true, 48);
        __syncthreads();

        // ---- feature: h1 -> hdW cols 0..31 (NO relu) ----
        Frag af; af.s = *(const short8*)&hW[r * 72 + 32 + kb];  // h1, reused for final
        f32x4 accf[2] = { {0.f,0.f,0.f,0.f}, {0.f,0.f,0.f,0.f} };
        accf[0] = MFMA16(af.b, Bf[0].b, accf[0]);
        accf[1] = MFMA16(af.b, Bf[1].b, accf[1]);
        store_cd(hdW, q, c, accf[0], bfv[0], false, 0);
        store_cd(hdW, q, c, accf[1], bfv[1], false, 16);
        __syncthreads();

        // ---- dir layer: [feature|dir] (K=64) -> hd -> hW cols 0..31 ----
        Frag ad0, ad1;
        ad0.s = *(const short8*)&hdW[r * 72 + kb];
        ad1.s = *(const short8*)&hdW[r * 72 + 32 + kb];
        f32x4 accd[2] = { {0.f,0.f,0.f,0.f}, {0.f,0.f,0.f,0.f} };
        accd[0] = MFMA16(ad0.b, Bd[0][0].b, accd[0]);
        accd[0] = MFMA16(ad1.b, Bd[0][1].b, accd[0]);
        accd[1] = MFMA16(ad0.b, Bd[1][0].b, accd[1]);
        accd[1] = MFMA16(ad1.b, Bd[1][1].b, accd[1]);
        store_cd(hW, q, c, accd[0], bdv[0], true, 0);
        store_cd(hW, q, c, accd[1], bdv[1], true, 16);
        __syncthreads();

        // ---- final: [h1 | hd] x WFin -> cols 0..3 = rgb, alpha ----
        Frag ah; ah.s = *(const short8*)&hW[r * 72 + kb];   // hd
        f32x4 accg = { 0.f, 0.f, 0.f, 0.f };
        accg = MFMA16(af.b, BF[0].b, accg);   // h1 part (k 0..31, Wa row)
        accg = MFMA16(ah.b, BF[1].b, accg);   // hd part (k 32..63, Wr rows)
        if (c < 4) {
#pragma unroll
            for (int rI = 0; rI < 4; rI++)
                oF[(q * 4 + rI) * 4 + c] = accg[rI] + bFinv;
        }
        __syncthreads();

        // coalesced fp32 store: 16 lanes x 16B = one 16-row out tile
        if (lane < 16) {
            ((float4*)Out)[row0 + lane] = *(const float4*)&oF[lane * 4];
        }
        __syncthreads();
    }
}

extern "C" void kernel_launch(void* const* d_in, const int* in_sizes, int n_in,
                              void* d_out, int out_size, void* d_ws, size_t ws_size,
                              hipStream_t stream) {
    kilonerf_kernel<<<4096, 256, 0, stream>>>(
        (const float*)d_in[0],
        (const float*)d_in[1], (const float*)d_in[2],
        (const float*)d_in[3], (const float*)d_in[4],
        (const float*)d_in[5], (const float*)d_in[6],
        (const float*)d_in[7], (const float*)d_in[8],
        (const float*)d_in[9], (const float*)d_in[10],
        (const float*)d_in[11], (const float*)d_in[12],
        (float*)d_out);
}